// Round 6
// baseline (1434.104 us; speedup 1.0000x reference)
//
#include <hip/hip_runtime.h>
#include <math.h>

#define N_NODES 100000
#define N_EDGES 3200000
#define F_NODE 4
#define F_EDGE 4
#define LD 6
#define HID 16
#define NLAYER 8
#define EPSF 1e-6f

#define NPB 64                      // nodes per bucket
#define NBK 1563                    // ceil(N_NODES/64)
#define G1 2000                     // blocks for hist/scatter
#define CH (N_EDGES / G1)           // 1600 edges per block
#define SBK 32                      // ceil(G1/64) per-thread vals in scanb

// ---------- bf16 helpers (RNE pack, low half = first elem) ----------
__device__ __forceinline__ unsigned f2bf(float a, float b) {
    unsigned ua = __float_as_uint(a);
    ua = (ua + 0x7fffu + ((ua >> 16) & 1u)) >> 16;
    unsigned ub = __float_as_uint(b);
    ub = (ub + 0x7fffu + ((ub >> 16) & 1u)) & 0xffff0000u;
    return ua | ub;
}
__device__ __forceinline__ float bflo(unsigned u) { return __uint_as_float(u << 16); }
__device__ __forceinline__ float bfhi(unsigned u) { return __uint_as_float(u & 0xffff0000u); }

// ==================== phase 1: per-block LDS histograms ====================
__global__ __launch_bounds__(256) void hist_kernel(const int* __restrict__ ei,
                                                   int* __restrict__ ghd,
                                                   int* __restrict__ ghs) {
    __shared__ int hd[NBK];
    __shared__ int hs[NBK];
    int t = threadIdx.x;
    for (int i = t; i < NBK; i += 256) { hd[i] = 0; hs[i] = 0; }
    __syncthreads();
    int beg = blockIdx.x * CH, end = beg + CH;
    for (int e = beg + t; e < end; e += 256) {
        atomicAdd(&hs[ei[e] >> 6], 1);
        atomicAdd(&hd[ei[N_EDGES + e] >> 6], 1);
    }
    __syncthreads();
    int* gd = ghd + (size_t)blockIdx.x * NBK;
    int* gs = ghs + (size_t)blockIdx.x * NBK;
    for (int i = t; i < NBK; i += 256) { gd[i] = hd[i]; gs[i] = hs[i]; }
}

// ==================== phase 2a: per-bucket scan over blocks ====================
__global__ __launch_bounds__(64) void scanb_kernel(int* __restrict__ ghd, int* __restrict__ ghs,
                                                   int* __restrict__ totd, int* __restrict__ tots) {
    int b = blockIdx.x, t = threadIdx.x;
#pragma unroll
    for (int a = 0; a < 2; a++) {
        int* g = a ? ghs : ghd;
        int vals[SBK];
        int sum = 0;
#pragma unroll
        for (int k = 0; k < SBK; k++) {
            int idx = t * SBK + k;
            vals[k] = (idx < G1) ? g[(size_t)idx * NBK + b] : 0;
            sum += vals[k];
        }
        int pre = sum;
        for (int off = 1; off < 64; off <<= 1) { int v = __shfl_up(pre, off, 64); if (t >= off) pre += v; }
        int excl = pre - sum;
        int tot = __shfl(pre, 63, 64);
#pragma unroll
        for (int k = 0; k < SBK; k++) {
            int idx = t * SBK + k;
            if (idx < G1) g[(size_t)idx * NBK + b] = excl;
            excl += vals[k];
        }
        if (t == 0) (a ? tots : totd)[b] = tot;
    }
}

// ==================== phase 2b: exclusive scan of bucket totals ====================
__global__ __launch_bounds__(256) void totscan_kernel(const int* __restrict__ totd,
                                                      const int* __restrict__ tots,
                                                      int* __restrict__ based,
                                                      int* __restrict__ bases) {
    __shared__ int part[256];
    int t = threadIdx.x;
#pragma unroll
    for (int a = 0; a < 2; a++) {
        const int* tot = a ? tots : totd;
        int* base = a ? bases : based;
        int loc[7];
        int sum = 0;
#pragma unroll
        for (int k = 0; k < 7; k++) { int i = t * 7 + k; loc[k] = (i < NBK) ? tot[i] : 0; sum += loc[k]; }
        part[t] = sum;
        __syncthreads();
        for (int off = 1; off < 256; off <<= 1) {
            int v = (t >= off) ? part[t - off] : 0;
            __syncthreads();
            part[t] += v;
            __syncthreads();
        }
        int excl = part[t] - sum;
#pragma unroll
        for (int k = 0; k < 7; k++) { int i = t * 7 + k; if (i < NBK) base[i] = excl; excl += loc[k]; }
        __syncthreads();
    }
}

// ==================== phase 3: binned scatter ====================
// rec word0 = src | (d&63)<<17 ; word1/2 = ea bf16x4 ; word3 = original edge id
// sbuf = e | (s&63)<<22
__global__ __launch_bounds__(256) void scatter_kernel(const int* __restrict__ ei,
                                                      const float* __restrict__ ea,
                                                      const int* __restrict__ ghd,
                                                      const int* __restrict__ ghs,
                                                      const int* __restrict__ based,
                                                      const int* __restrict__ bases,
                                                      uint4* __restrict__ rec,
                                                      unsigned* __restrict__ sbuf) {
    __shared__ int curd[NBK];
    __shared__ int curs[NBK];
    int t = threadIdx.x, blk = blockIdx.x;
    const int* gd = ghd + (size_t)blk * NBK;
    const int* gs = ghs + (size_t)blk * NBK;
    for (int i = t; i < NBK; i += 256) { curd[i] = based[i] + gd[i]; curs[i] = bases[i] + gs[i]; }
    __syncthreads();
    int beg = blk * CH, end = beg + CH;
    for (int e = beg + t; e < end; e += 256) {
        int s = ei[e], d = ei[N_EDGES + e];
        float4 ev = reinterpret_cast<const float4*>(ea)[e];
        int p = atomicAdd(&curd[d >> 6], 1);
        rec[p] = make_uint4((unsigned)s | ((unsigned)(d & 63) << 17),
                            f2bf(ev.x, ev.y), f2bf(ev.z, ev.w), (unsigned)e);
        int q = atomicAdd(&curs[s >> 6], 1);
        sbuf[q] = (unsigned)e | ((unsigned)(s & 63) << 22);
    }
}

// ==================== layer-0 A/B tables ====================
__global__ __launch_bounds__(256) void ab_init(const float* __restrict__ x,
                                               const float* __restrict__ W1,
                                               const float* __restrict__ b1,
                                               unsigned* __restrict__ A,
                                               unsigned* __restrict__ B) {
    __shared__ float sW[8 * HID];
    __shared__ float sb[HID];
    int t = threadIdx.x;
    for (int i = t; i < 8 * HID; i += 256) sW[i] = W1[12 * HID + i];
    if (t < HID) sb[t] = b1[t];
    __syncthreads();
    int i = blockIdx.x * 256 + t;
    if (i >= N_NODES) return;
    float4 xv = reinterpret_cast<const float4*>(x)[i];
    float xf[4] = {xv.x, xv.y, xv.z, xv.w};
    float a[HID], bb[HID];
#pragma unroll
    for (int j = 0; j < HID; j++) { a[j] = sb[j]; bb[j] = 0.0f; }
#pragma unroll
    for (int r = 0; r < 4; r++) {
        float v = xf[r];
#pragma unroll
        for (int j = 0; j < HID; j++) {
            a[j]  = fmaf(v, sW[r * HID + j], a[j]);
            bb[j] = fmaf(v, sW[(4 + r) * HID + j], bb[j]);
        }
    }
    uint4* Ao = reinterpret_cast<uint4*>(A + (size_t)i * 8);
    Ao[0] = make_uint4(f2bf(a[0], a[1]), f2bf(a[2], a[3]), f2bf(a[4], a[5]), f2bf(a[6], a[7]));
    Ao[1] = make_uint4(f2bf(a[8], a[9]), f2bf(a[10], a[11]), f2bf(a[12], a[13]), f2bf(a[14], a[15]));
    uint4* Bo = reinterpret_cast<uint4*>(B + (size_t)i * 8);
    Bo[0] = make_uint4(f2bf(bb[0], bb[1]), f2bf(bb[2], bb[3]), f2bf(bb[4], bb[5]), f2bf(bb[6], bb[7]));
    Bo[1] = make_uint4(f2bf(bb[8], bb[9]), f2bf(bb[10], bb[11]), f2bf(bb[12], bb[13]), f2bf(bb[14], bb[15]));
}

// ==================== per-layer kernel: chunked run-accumulation ====================
template <int LAST>
__global__ __launch_bounds__(256) void edge_layer(const uint4* __restrict__ rec,
                                                  const unsigned* __restrict__ Ain,
                                                  const unsigned* __restrict__ Bin,
                                                  const float* __restrict__ x,
                                                  const float* __restrict__ W1l,
                                                  const float* __restrict__ W2l,
                                                  const float* __restrict__ b2l,
                                                  const float* __restrict__ W1n,
                                                  const float* __restrict__ b1n,
                                                  const float* __restrict__ Wf,
                                                  const float* __restrict__ bfp,
                                                  const int* __restrict__ based,
                                                  const int* __restrict__ totd,
                                                  unsigned* __restrict__ Aout,
                                                  unsigned* __restrict__ Bout,
                                                  float* __restrict__ Pout,
                                                  float* __restrict__ Pbuf) {
    __shared__ float sWea[4 * HID];
    __shared__ float sW2[HID * LD];
    __shared__ float sb2[LD];
    __shared__ float sW1n[20 * HID];
    __shared__ float sb1n[HID];
    __shared__ float sWf[LD];
    __shared__ float sbf;
    __shared__ float accf[LD * NPB];
    __shared__ int scnt[NPB];
    int t = threadIdx.x;
    for (int i = t; i < 4 * HID; i += 256) sWea[i] = W1l[20 * HID + i];
    for (int i = t; i < HID * LD; i += 256) sW2[i] = W2l[i];
    if (t < LD) sb2[t] = b2l[t];
    if (!LAST) {
        for (int i = t; i < 20 * HID; i += 256) sW1n[i] = W1n[i];
        if (t < HID) sb1n[t] = b1n[t];
    } else {
        if (t < LD) sWf[t] = Wf[t];
        if (t == 0) sbf = bfp[0];
    }
    for (int i = t; i < LD * NPB; i += 256) accf[i] = 0.0f;
    if (t < NPB) scnt[t] = 0;
    __syncthreads();

    int b = blockIdx.x;
    int beg = based[b], tot = totd[b];
    int K = (tot + 255) >> 8;
    int p0 = beg + t * K;
    int p1 = p0 + K;
    int pend = beg + tot;
    if (p1 > pend) p1 = pend;

    float acc[LD];
    int cnt = 0;
    int curdl = -1;
    uint4 brow0, brow1;
#pragma unroll
    for (int o = 0; o < LD; o++) acc[o] = 0.0f;

    for (int p = p0; p < p1; ++p) {
        uint4 r = rec[p];
        int s  = (int)(r.x & 0x1FFFFu);
        int dl = (int)(r.x >> 17) & 63;
        if (dl != curdl) {
            if (cnt) {
#pragma unroll
                for (int o = 0; o < LD; o++) atomicAdd(&accf[o * NPB + curdl], acc[o]);
                atomicAdd(&scnt[curdl], cnt);
            }
            curdl = dl;
            cnt = 0;
#pragma unroll
            for (int o = 0; o < LD; o++) acc[o] = 0.0f;
            const uint4* Bp = reinterpret_cast<const uint4*>(Bin + (size_t)((b << 6) + dl) * 8);
            brow0 = Bp[0];
            brow1 = Bp[1];
        }
        const uint4* Ap = reinterpret_cast<const uint4*>(Ain + (size_t)s * 8);
        uint4 ax = Ap[0], ay = Ap[1];
        float h[HID];
        h[0]  = bflo(ax.x) + bflo(brow0.x);  h[1]  = bfhi(ax.x) + bfhi(brow0.x);
        h[2]  = bflo(ax.y) + bflo(brow0.y);  h[3]  = bfhi(ax.y) + bfhi(brow0.y);
        h[4]  = bflo(ax.z) + bflo(brow0.z);  h[5]  = bfhi(ax.z) + bfhi(brow0.z);
        h[6]  = bflo(ax.w) + bflo(brow0.w);  h[7]  = bfhi(ax.w) + bfhi(brow0.w);
        h[8]  = bflo(ay.x) + bflo(brow1.x);  h[9]  = bfhi(ay.x) + bfhi(brow1.x);
        h[10] = bflo(ay.y) + bflo(brow1.y);  h[11] = bfhi(ay.y) + bfhi(brow1.y);
        h[12] = bflo(ay.z) + bflo(brow1.z);  h[13] = bfhi(ay.z) + bfhi(brow1.z);
        h[14] = bflo(ay.w) + bflo(brow1.w);  h[15] = bfhi(ay.w) + bfhi(brow1.w);
        float ef[4] = {bflo(r.y), bfhi(r.y), bflo(r.z), bfhi(r.z)};
#pragma unroll
        for (int rr = 0; rr < 4; rr++) {
            float v = ef[rr];
#pragma unroll
            for (int j = 0; j < HID; j++) h[j] = fmaf(v, sWea[rr * HID + j], h[j]);
        }
#pragma unroll
        for (int j = 0; j < HID; j++) h[j] = fmaxf(h[j], 0.0f);
        float m[LD];
#pragma unroll
        for (int o = 0; o < LD; o++) m[o] = sb2[o];
#pragma unroll
        for (int j = 0; j < HID; j++) {
            float hj = h[j];
#pragma unroll
            for (int o = 0; o < LD; o++) m[o] = fmaf(hj, sW2[j * LD + o], m[o]);
        }
#pragma unroll
        for (int o = 0; o < LD; o++) acc[o] += m[o];
        cnt++;
    }
    if (cnt) {
#pragma unroll
        for (int o = 0; o < LD; o++) atomicAdd(&accf[o * NPB + curdl], acc[o]);
        atomicAdd(&scnt[curdl], cnt);
    }
    __syncthreads();

    if (t < NPB) {
        int gid = (b << 6) + t;
        if (gid < N_NODES) {
            float inv = 1.0f / fmaxf((float)scnt[t], 1.0f);
            float Xv[LD];
#pragma unroll
            for (int o = 0; o < LD; o++) Xv[o] = fmaxf(accf[o * NPB + t] * inv, 0.0f);
            if (LAST) {
                float a2 = sbf;
#pragma unroll
                for (int o = 0; o < LD; o++) a2 = fmaf(Xv[o], sWf[o], a2);
                float P = fmaxf(a2, 0.0f);
                Pout[gid] = P;
                float fx = x[gid * F_NODE + 3];
                Pbuf[gid] = (fx != 0.0f) ? fx : P;
            } else {
                float4 xv = reinterpret_cast<const float4*>(x)[gid];
                float xf[4] = {xv.x, xv.y, xv.z, xv.w};
                float a[HID], bb[HID];
#pragma unroll
                for (int j = 0; j < HID; j++) { a[j] = sb1n[j]; bb[j] = 0.0f; }
#pragma unroll
                for (int rr = 0; rr < LD; rr++) {
                    float v = Xv[rr];
#pragma unroll
                    for (int j = 0; j < HID; j++) {
                        a[j]  = fmaf(v, sW1n[rr * HID + j], a[j]);
                        bb[j] = fmaf(v, sW1n[(LD + rr) * HID + j], bb[j]);
                    }
                }
#pragma unroll
                for (int rr = 0; rr < 4; rr++) {
                    float v = xf[rr];
#pragma unroll
                    for (int j = 0; j < HID; j++) {
                        a[j]  = fmaf(v, sW1n[(12 + rr) * HID + j], a[j]);
                        bb[j] = fmaf(v, sW1n[(16 + rr) * HID + j], bb[j]);
                    }
                }
                uint4* Ao = reinterpret_cast<uint4*>(Aout + (size_t)gid * 8);
                Ao[0] = make_uint4(f2bf(a[0], a[1]), f2bf(a[2], a[3]), f2bf(a[4], a[5]), f2bf(a[6], a[7]));
                Ao[1] = make_uint4(f2bf(a[8], a[9]), f2bf(a[10], a[11]), f2bf(a[12], a[13]), f2bf(a[14], a[15]));
                uint4* Bo = reinterpret_cast<uint4*>(Bout + (size_t)gid * 8);
                Bo[0] = make_uint4(f2bf(bb[0], bb[1]), f2bf(bb[2], bb[3]), f2bf(bb[4], bb[5]), f2bf(bb[6], bb[7]));
                Bo[1] = make_uint4(f2bf(bb[8], bb[9]), f2bf(bb[10], bb[11]), f2bf(bb[12], bb[13]), f2bf(bb[14], bb[15]));
            }
        }
    }
}

// ==================== flows (original order, exact fp32) ====================
__global__ __launch_bounds__(256) void flows_noatomic(const int* __restrict__ ei,
                                                      const float* __restrict__ ea,
                                                      const float* __restrict__ Pbuf,
                                                      float* __restrict__ flows_out) {
    int e = blockIdx.x * 256 + threadIdx.x;
    if (e >= N_EDGES) return;
    int s = ei[e];
    int d = ei[N_EDGES + e];
    float ps = Pbuf[s], pd = Pbuf[d];
    float dp2 = ps * ps - pd * pd;
    float k = ea[(size_t)e * F_EDGE];
    float sg = (dp2 > 0.0f) ? 1.0f : ((dp2 < 0.0f) ? -1.0f : 0.0f);
    flows_out[e] = sg * sqrtf(fabsf(dp2) / k + EPSF);
}

// ==================== balance in-flow (chunked run-accumulation) ====================
__global__ __launch_bounds__(256) void balance_in(const uint4* __restrict__ rec,
                                                  const float* __restrict__ flows,
                                                  const float* __restrict__ x,
                                                  const int* __restrict__ based,
                                                  const int* __restrict__ totd,
                                                  float* __restrict__ bal) {
    __shared__ float acc[NPB];
    int t = threadIdx.x;
    if (t < NPB) acc[t] = 0.0f;
    __syncthreads();
    int b = blockIdx.x;
    int beg = based[b], tot = totd[b];
    int K = (tot + 255) >> 8;
    int p0 = beg + t * K;
    int p1 = p0 + K;
    int pend = beg + tot;
    if (p1 > pend) p1 = pend;
    float ar = 0.0f;
    int cur = -1;
    for (int p = p0; p < p1; ++p) {
        uint4 r = rec[p];
        int dl = (int)(r.x >> 17) & 63;
        float f = flows[r.w];
        if (dl != cur) {
            if (cur >= 0) atomicAdd(&acc[cur], ar);
            cur = dl;
            ar = 0.0f;
        }
        ar += f;
    }
    if (cur >= 0) atomicAdd(&acc[cur], ar);
    __syncthreads();
    if (t < NPB) {
        int gid = (b << 6) + t;
        if (gid < N_NODES) bal[gid] = acc[t] + x[gid * F_NODE + 0];
    }
}

// ==================== balance out-flow + imbalance partial ====================
__global__ __launch_bounds__(256) void balance_out(const unsigned* __restrict__ sbuf,
                                                   const float* __restrict__ flows,
                                                   const int* __restrict__ bases,
                                                   const int* __restrict__ tots,
                                                   const float* __restrict__ bal,
                                                   float* __restrict__ imb2) {
    __shared__ float acc[NPB];
    int t = threadIdx.x;
    if (t < NPB) acc[t] = 0.0f;
    __syncthreads();
    int b = blockIdx.x;
    int beg = bases[b], end = beg + tots[b];
    for (int q = beg + t; q < end; q += 256) {
        unsigned u = sbuf[q];
        atomicAdd(&acc[(u >> 22) & 63u], flows[u & 0x3FFFFFu]);
    }
    __syncthreads();
    if (t < NPB) {
        float v = 0.0f;
        int gid = (b << 6) + t;
        if (gid < N_NODES) {
            float bv = bal[gid] - acc[t];
            v = bv * bv;
        }
#pragma unroll
        for (int off = 32; off > 0; off >>= 1) v += __shfl_down(v, off, 64);
        if (t == 0) atomicAdd(imb2, v);
    }
}

__global__ void fin_kernel(const float* __restrict__ imb2, float* __restrict__ out) {
    out[0] = sqrtf(imb2[0]);
}

// ==================== launch ====================
extern "C" void kernel_launch(void* const* d_in, const int* in_sizes, int n_in,
                              void* d_out, int out_size, void* d_ws, size_t ws_size,
                              hipStream_t stream) {
    const float* x   = (const float*)d_in[0];
    const float* ea  = (const float*)d_in[1];
    const int*   ei  = (const int*)d_in[2];
    const float* W1  = (const float*)d_in[3];
    const float* b1  = (const float*)d_in[4];
    const float* W2  = (const float*)d_in[5];
    const float* b2  = (const float*)d_in[6];
    const float* Wf  = (const float*)d_in[7];
    const float* bf_ = (const float*)d_in[8];
    float* out = (float*)d_out;

    const size_t N = N_NODES, E = N_EDGES;

    // ---- workspace layout (4B elements), ~103 MB ----
    size_t o = 0;
    auto alloc = [&](size_t n) { size_t r = o; o += (n + 3) & ~(size_t)3; return r; };
    size_t o_rec   = alloc(4 * E);
    size_t o_sbuf  = alloc(E);
    size_t o_ghd   = alloc((size_t)G1 * NBK);
    size_t o_ghs   = alloc((size_t)G1 * NBK);
    size_t o_totd  = alloc(NBK);
    size_t o_tots  = alloc(NBK);
    size_t o_based = alloc(NBK);
    size_t o_bases = alloc(NBK);
    size_t o_A0    = alloc(8 * N);
    size_t o_B0    = alloc(8 * N);
    size_t o_A1    = alloc(8 * N);
    size_t o_B1    = alloc(8 * N);
    size_t o_Pbuf  = alloc(N);
    size_t o_bal   = alloc(N);
    size_t o_imb2  = alloc(16);
    (void)o;

    int* wsi = (int*)d_ws;
    uint4*    rec   = (uint4*)(wsi + o_rec);
    unsigned* sbuf  = (unsigned*)(wsi + o_sbuf);
    int*      ghd   = wsi + o_ghd;
    int*      ghs   = wsi + o_ghs;
    int*      totd  = wsi + o_totd;
    int*      tots  = wsi + o_tots;
    int*      based = wsi + o_based;
    int*      bases = wsi + o_bases;
    unsigned* A0    = (unsigned*)(wsi + o_A0);
    unsigned* B0    = (unsigned*)(wsi + o_B0);
    unsigned* A1    = (unsigned*)(wsi + o_A1);
    unsigned* B1    = (unsigned*)(wsi + o_B1);
    float*    Pbuf  = (float*)(wsi + o_Pbuf);
    float*    bal   = (float*)(wsi + o_bal);
    float*    imb2  = (float*)(wsi + o_imb2);

    const int NB = (N_NODES + 255) / 256;   // 391
    const int EB = (N_EDGES + 255) / 256;   // 12500

    hipMemsetAsync(imb2, 0, sizeof(float), stream);

    hist_kernel<<<G1, 256, 0, stream>>>(ei, ghd, ghs);
    scanb_kernel<<<NBK, 64, 0, stream>>>(ghd, ghs, totd, tots);
    totscan_kernel<<<1, 256, 0, stream>>>(totd, tots, based, bases);
    scatter_kernel<<<G1, 256, 0, stream>>>(ei, ea, ghd, ghs, based, bases, rec, sbuf);

    ab_init<<<NB, 256, 0, stream>>>(x, W1, b1, A0, B0);

    for (int l = 0; l < NLAYER; l++) {
        const unsigned* Ain = (l & 1) ? A1 : A0;
        const unsigned* Bin = (l & 1) ? B1 : B0;
        unsigned* Aout = (l & 1) ? A0 : A1;
        unsigned* Bout = (l & 1) ? B0 : B1;
        const float* W1l = W1 + (size_t)l * 24 * HID;
        const float* W2l = W2 + (size_t)l * HID * LD;
        const float* b2l = b2 + (size_t)l * LD;
        if (l < NLAYER - 1) {
            edge_layer<0><<<NBK, 256, 0, stream>>>(rec, Ain, Bin, x, W1l, W2l, b2l,
                                                   W1 + (size_t)(l + 1) * 24 * HID,
                                                   b1 + (size_t)(l + 1) * HID,
                                                   Wf, bf_, based, totd,
                                                   Aout, Bout, out, Pbuf);
        } else {
            edge_layer<1><<<NBK, 256, 0, stream>>>(rec, Ain, Bin, x, W1l, W2l, b2l,
                                                   W1, b1, Wf, bf_, based, totd,
                                                   Aout, Bout, out, Pbuf);
        }
    }

    flows_noatomic<<<EB, 256, 0, stream>>>(ei, ea, Pbuf, out + N);
    balance_in<<<NBK, 256, 0, stream>>>(rec, out + N, x, based, totd, bal);
    balance_out<<<NBK, 256, 0, stream>>>(sbuf, out + N, bases, tots, bal, imb2);
    fin_kernel<<<1, 1, 0, stream>>>(imb2, out + (size_t)N + E);
}

// Round 7
// 923.793 us; speedup vs baseline: 1.5524x; 1.5524x over previous
//
#include <hip/hip_runtime.h>
#include <math.h>

#define N_NODES 100000
#define N_EDGES 3200000
#define F_NODE 4
#define F_EDGE 4
#define LD 6
#define HID 16
#define NLAYER 8
#define EPSF 1e-6f

#define NPB 64                      // nodes per bucket
#define NBK 1563                    // ceil(N_NODES/64)
#define G1 2000                     // blocks for hist/scatter
#define CH (N_EDGES / G1)           // 1600 edges per block
#define SBK 32                      // ceil(G1/64) per-thread vals in scanb
#define CAP 3072                    // sort staging capacity (edges per bucket)

// ---------- bf16 helpers (RNE pack, low half = first elem) ----------
__device__ __forceinline__ unsigned f2bf(float a, float b) {
    unsigned ua = __float_as_uint(a);
    ua = (ua + 0x7fffu + ((ua >> 16) & 1u)) >> 16;
    unsigned ub = __float_as_uint(b);
    ub = (ub + 0x7fffu + ((ub >> 16) & 1u)) & 0xffff0000u;
    return ua | ub;
}
__device__ __forceinline__ float bflo(unsigned u) { return __uint_as_float(u << 16); }
__device__ __forceinline__ float bfhi(unsigned u) { return __uint_as_float(u & 0xffff0000u); }

// ==================== phase 1: per-block LDS histograms ====================
__global__ __launch_bounds__(256) void hist_kernel(const int* __restrict__ ei,
                                                   int* __restrict__ ghd,
                                                   int* __restrict__ ghs) {
    __shared__ int hd[NBK];
    __shared__ int hs[NBK];
    int t = threadIdx.x;
    for (int i = t; i < NBK; i += 256) { hd[i] = 0; hs[i] = 0; }
    __syncthreads();
    int beg = blockIdx.x * CH, end = beg + CH;
    for (int e = beg + t; e < end; e += 256) {
        atomicAdd(&hs[ei[e] >> 6], 1);
        atomicAdd(&hd[ei[N_EDGES + e] >> 6], 1);
    }
    __syncthreads();
    int* gd = ghd + (size_t)blockIdx.x * NBK;
    int* gs = ghs + (size_t)blockIdx.x * NBK;
    for (int i = t; i < NBK; i += 256) { gd[i] = hd[i]; gs[i] = hs[i]; }
}

// ==================== phase 2a: per-bucket scan over blocks ====================
__global__ __launch_bounds__(64) void scanb_kernel(int* __restrict__ ghd, int* __restrict__ ghs,
                                                   int* __restrict__ totd, int* __restrict__ tots) {
    int b = blockIdx.x, t = threadIdx.x;
#pragma unroll
    for (int a = 0; a < 2; a++) {
        int* g = a ? ghs : ghd;
        int vals[SBK];
        int sum = 0;
#pragma unroll
        for (int k = 0; k < SBK; k++) {
            int idx = t * SBK + k;
            vals[k] = (idx < G1) ? g[(size_t)idx * NBK + b] : 0;
            sum += vals[k];
        }
        int pre = sum;
        for (int off = 1; off < 64; off <<= 1) { int v = __shfl_up(pre, off, 64); if (t >= off) pre += v; }
        int excl = pre - sum;
        int tot = __shfl(pre, 63, 64);
#pragma unroll
        for (int k = 0; k < SBK; k++) {
            int idx = t * SBK + k;
            if (idx < G1) g[(size_t)idx * NBK + b] = excl;
            excl += vals[k];
        }
        if (t == 0) (a ? tots : totd)[b] = tot;
    }
}

// ==================== phase 2b: exclusive scan of bucket totals ====================
__global__ __launch_bounds__(256) void totscan_kernel(const int* __restrict__ totd,
                                                      const int* __restrict__ tots,
                                                      int* __restrict__ based,
                                                      int* __restrict__ bases) {
    __shared__ int part[256];
    int t = threadIdx.x;
#pragma unroll
    for (int a = 0; a < 2; a++) {
        const int* tot = a ? tots : totd;
        int* base = a ? bases : based;
        int loc[7];
        int sum = 0;
#pragma unroll
        for (int k = 0; k < 7; k++) { int i = t * 7 + k; loc[k] = (i < NBK) ? tot[i] : 0; sum += loc[k]; }
        part[t] = sum;
        __syncthreads();
        for (int off = 1; off < 256; off <<= 1) {
            int v = (t >= off) ? part[t - off] : 0;
            __syncthreads();
            part[t] += v;
            __syncthreads();
        }
        int excl = part[t] - sum;
#pragma unroll
        for (int k = 0; k < 7; k++) { int i = t * 7 + k; if (i < NBK) base[i] = excl; excl += loc[k]; }
        __syncthreads();
    }
}

// ==================== phase 3: binned scatter ====================
// rec word0 = src | (d&63)<<17 ; word1/2 = ea bf16x4 ; word3 = original edge id
// sbuf = e | (s&63)<<22
__global__ __launch_bounds__(256) void scatter_kernel(const int* __restrict__ ei,
                                                      const float* __restrict__ ea,
                                                      const int* __restrict__ ghd,
                                                      const int* __restrict__ ghs,
                                                      const int* __restrict__ based,
                                                      const int* __restrict__ bases,
                                                      uint4* __restrict__ rec,
                                                      unsigned* __restrict__ sbuf) {
    __shared__ int curd[NBK];
    __shared__ int curs[NBK];
    int t = threadIdx.x, blk = blockIdx.x;
    const int* gd = ghd + (size_t)blk * NBK;
    const int* gs = ghs + (size_t)blk * NBK;
    for (int i = t; i < NBK; i += 256) { curd[i] = based[i] + gd[i]; curs[i] = bases[i] + gs[i]; }
    __syncthreads();
    int beg = blk * CH, end = beg + CH;
    for (int e = beg + t; e < end; e += 256) {
        int s = ei[e], d = ei[N_EDGES + e];
        float4 ev = reinterpret_cast<const float4*>(ea)[e];
        int p = atomicAdd(&curd[d >> 6], 1);
        rec[p] = make_uint4((unsigned)s | ((unsigned)(d & 63) << 17),
                            f2bf(ev.x, ev.y), f2bf(ev.z, ev.w), (unsigned)e);
        int q = atomicAdd(&curs[s >> 6], 1);
        sbuf[q] = (unsigned)e | ((unsigned)(s & 63) << 22);
    }
}

// ==================== phase 4: in-bucket counting sort by dl (+ degInv) ====================
__global__ __launch_bounds__(256) void sort_kernel(uint4* __restrict__ rec,
                                                   const int* __restrict__ based,
                                                   const int* __restrict__ totd,
                                                   float* __restrict__ degInv) {
    __shared__ uint4 stage[CAP];
    __shared__ int hist[NPB];
    __shared__ int cur[NPB];
    int b = blockIdx.x, t = threadIdx.x;
    int beg = based[b], tot = totd[b];
    if (t < NPB) hist[t] = 0;
    __syncthreads();
    bool fits = tot <= CAP;
    for (int i = t; i < tot; i += 256) {
        uint4 r = rec[beg + i];
        if (fits) stage[i] = r;
        atomicAdd(&hist[(r.x >> 17) & 63u], 1);
    }
    __syncthreads();
    if (t < NPB) {
        int gid = (b << 6) + t;
        if (gid < N_NODES) degInv[gid] = 1.0f / fmaxf((float)hist[t], 1.0f);
        // exclusive scan of hist[64] within wave 0
        int v = hist[t];
        int pre = v;
#pragma unroll
        for (int off = 1; off < 64; off <<= 1) {
            int u = __shfl_up(pre, off, 64);
            if (t >= off) pre += u;
        }
        cur[t] = pre - v;
    }
    __syncthreads();
    if (fits) {
        for (int i = t; i < tot; i += 256) {
            uint4 r = stage[i];
            int p = atomicAdd(&cur[(r.x >> 17) & 63u], 1);
            rec[beg + p] = r;
        }
    }
}

// ==================== layer-0 A/B tables ====================
__global__ __launch_bounds__(256) void ab_init(const float* __restrict__ x,
                                               const float* __restrict__ W1,
                                               const float* __restrict__ b1,
                                               unsigned* __restrict__ A,
                                               unsigned* __restrict__ B) {
    __shared__ float sW[8 * HID];
    __shared__ float sb[HID];
    int t = threadIdx.x;
    for (int i = t; i < 8 * HID; i += 256) sW[i] = W1[12 * HID + i];
    if (t < HID) sb[t] = b1[t];
    __syncthreads();
    int i = blockIdx.x * 256 + t;
    if (i >= N_NODES) return;
    float4 xv = reinterpret_cast<const float4*>(x)[i];
    float xf[4] = {xv.x, xv.y, xv.z, xv.w};
    float a[HID], bb[HID];
#pragma unroll
    for (int j = 0; j < HID; j++) { a[j] = sb[j]; bb[j] = 0.0f; }
#pragma unroll
    for (int r = 0; r < 4; r++) {
        float v = xf[r];
#pragma unroll
        for (int j = 0; j < HID; j++) {
            a[j]  = fmaf(v, sW[r * HID + j], a[j]);
            bb[j] = fmaf(v, sW[(4 + r) * HID + j], bb[j]);
        }
    }
    uint4* Ao = reinterpret_cast<uint4*>(A + (size_t)i * 8);
    Ao[0] = make_uint4(f2bf(a[0], a[1]), f2bf(a[2], a[3]), f2bf(a[4], a[5]), f2bf(a[6], a[7]));
    Ao[1] = make_uint4(f2bf(a[8], a[9]), f2bf(a[10], a[11]), f2bf(a[12], a[13]), f2bf(a[14], a[15]));
    uint4* Bo = reinterpret_cast<uint4*>(B + (size_t)i * 8);
    Bo[0] = make_uint4(f2bf(bb[0], bb[1]), f2bf(bb[2], bb[3]), f2bf(bb[4], bb[5]), f2bf(bb[6], bb[7]));
    Bo[1] = make_uint4(f2bf(bb[8], bb[9]), f2bf(bb[10], bb[11]), f2bf(bb[12], bb[13]), f2bf(bb[14], bb[15]));
}

// ==================== per-layer: 1 edge/thread, wave segscan, LDS flush ====================
template <int LAST>
__global__ __launch_bounds__(256) void edge_layer(const uint4* __restrict__ rec,
                                                  const unsigned* __restrict__ Ain,
                                                  const unsigned* __restrict__ Bin,
                                                  const float* __restrict__ x,
                                                  const float* __restrict__ degInv,
                                                  const float* __restrict__ W1l,
                                                  const float* __restrict__ W2l,
                                                  const float* __restrict__ b2l,
                                                  const float* __restrict__ W1n,
                                                  const float* __restrict__ b1n,
                                                  const float* __restrict__ Wf,
                                                  const float* __restrict__ bfp,
                                                  const int* __restrict__ based,
                                                  const int* __restrict__ totd,
                                                  unsigned* __restrict__ Aout,
                                                  unsigned* __restrict__ Bout,
                                                  float* __restrict__ Pout,
                                                  float* __restrict__ Pbuf) {
    __shared__ float sWea[4 * HID];
    __shared__ float sW2[HID * LD];
    __shared__ float sb2[LD];
    __shared__ float sW1n[20 * HID];
    __shared__ float sb1n[HID];
    __shared__ float sWf[LD];
    __shared__ float sbf;
    __shared__ float accf[LD * NPB];
    __shared__ unsigned sB[NPB * 8];
    int t = threadIdx.x;
    int b = blockIdx.x;
    for (int i = t; i < 4 * HID; i += 256) sWea[i] = W1l[20 * HID + i];
    for (int i = t; i < HID * LD; i += 256) sW2[i] = W2l[i];
    if (t < LD) sb2[t] = b2l[t];
    if (!LAST) {
        for (int i = t; i < 20 * HID; i += 256) sW1n[i] = W1n[i];
        if (t < HID) sb1n[t] = b1n[t];
    } else {
        if (t < LD) sWf[t] = Wf[t];
        if (t == 0) sbf = bfp[0];
    }
    for (int i = t; i < LD * NPB; i += 256) accf[i] = 0.0f;
    {   // stage this bucket's B rows (coalesced: Bin is dense row-major)
        size_t base8 = (size_t)(b << 6) * 8;
        for (int i = t; i < NPB * 8; i += 256) {
            size_t gi = base8 + i;
            sB[i] = (gi < (size_t)N_NODES * 8) ? Bin[gi] : 0u;
        }
    }
    __syncthreads();

    int beg = based[b], tot = totd[b];
    int end = beg + tot;
    int lane = t & 63;

    for (int base = beg; base < end; base += 256) {
        int p = base + t;
        bool valid = p < end;
        int key = -1;
        float out[LD];
#pragma unroll
        for (int o = 0; o < LD; o++) out[o] = 0.0f;

        if (valid) {
            uint4 r = rec[p];
            int s = (int)(r.x & 0x1FFFFu);
            key = (int)((r.x >> 17) & 63u);
            const uint4* Ap = reinterpret_cast<const uint4*>(Ain + (size_t)s * 8);
            uint4 ax = Ap[0], ay = Ap[1];
            const uint4* Bp = reinterpret_cast<const uint4*>(sB) + key * 2;
            uint4 bx = Bp[0], by = Bp[1];
            float h[HID];
            h[0]  = bflo(ax.x) + bflo(bx.x);  h[1]  = bfhi(ax.x) + bfhi(bx.x);
            h[2]  = bflo(ax.y) + bflo(bx.y);  h[3]  = bfhi(ax.y) + bfhi(bx.y);
            h[4]  = bflo(ax.z) + bflo(bx.z);  h[5]  = bfhi(ax.z) + bfhi(bx.z);
            h[6]  = bflo(ax.w) + bflo(bx.w);  h[7]  = bfhi(ax.w) + bfhi(bx.w);
            h[8]  = bflo(ay.x) + bflo(by.x);  h[9]  = bfhi(ay.x) + bfhi(by.x);
            h[10] = bflo(ay.y) + bflo(by.y);  h[11] = bfhi(ay.y) + bfhi(by.y);
            h[12] = bflo(ay.z) + bflo(by.z);  h[13] = bfhi(ay.z) + bfhi(by.z);
            h[14] = bflo(ay.w) + bflo(by.w);  h[15] = bfhi(ay.w) + bfhi(by.w);
            float ef[4] = {bflo(r.y), bfhi(r.y), bflo(r.z), bfhi(r.z)};
#pragma unroll
            for (int rr = 0; rr < 4; rr++) {
                float v = ef[rr];
#pragma unroll
                for (int j = 0; j < HID; j++) h[j] = fmaf(v, sWea[rr * HID + j], h[j]);
            }
#pragma unroll
            for (int j = 0; j < HID; j++) h[j] = fmaxf(h[j], 0.0f);
#pragma unroll
            for (int o = 0; o < LD; o++) out[o] = sb2[o];
#pragma unroll
            for (int j = 0; j < HID; j++) {
                float hj = h[j];
#pragma unroll
                for (int o = 0; o < LD; o++) out[o] = fmaf(hj, sW2[j * LD + o], out[o]);
            }
        }

        // wave segmented inclusive sum keyed on dl (sorted within bucket)
#pragma unroll
        for (int st = 1; st < 64; st <<= 1) {
            int kup = __shfl_up(key, st, 64);
            bool same = (lane >= st) && (kup == key);
#pragma unroll
            for (int o = 0; o < LD; o++) {
                float v = __shfl_up(out[o], st, 64);
                if (same) out[o] += v;
            }
        }
        int knx = __shfl_down(key, 1, 64);
        bool tail = (lane == 63) || (knx != key);
        if (valid && tail) {
#pragma unroll
            for (int o = 0; o < LD; o++) atomicAdd(&accf[o * NPB + key], out[o]);
        }
    }
    __syncthreads();

    if (t < NPB) {
        int gid = (b << 6) + t;
        if (gid < N_NODES) {
            float inv = degInv[gid];
            float Xv[LD];
#pragma unroll
            for (int o = 0; o < LD; o++) Xv[o] = fmaxf(accf[o * NPB + t] * inv, 0.0f);
            if (LAST) {
                float a2 = sbf;
#pragma unroll
                for (int o = 0; o < LD; o++) a2 = fmaf(Xv[o], sWf[o], a2);
                float P = fmaxf(a2, 0.0f);
                Pout[gid] = P;
                float fx = x[gid * F_NODE + 3];
                Pbuf[gid] = (fx != 0.0f) ? fx : P;
            } else {
                float4 xv = reinterpret_cast<const float4*>(x)[gid];
                float xf[4] = {xv.x, xv.y, xv.z, xv.w};
                float a[HID], bb[HID];
#pragma unroll
                for (int j = 0; j < HID; j++) { a[j] = sb1n[j]; bb[j] = 0.0f; }
#pragma unroll
                for (int rr = 0; rr < LD; rr++) {
                    float v = Xv[rr];
#pragma unroll
                    for (int j = 0; j < HID; j++) {
                        a[j]  = fmaf(v, sW1n[rr * HID + j], a[j]);
                        bb[j] = fmaf(v, sW1n[(LD + rr) * HID + j], bb[j]);
                    }
                }
#pragma unroll
                for (int rr = 0; rr < 4; rr++) {
                    float v = xf[rr];
#pragma unroll
                    for (int j = 0; j < HID; j++) {
                        a[j]  = fmaf(v, sW1n[(12 + rr) * HID + j], a[j]);
                        bb[j] = fmaf(v, sW1n[(16 + rr) * HID + j], bb[j]);
                    }
                }
                uint4* Ao = reinterpret_cast<uint4*>(Aout + (size_t)gid * 8);
                Ao[0] = make_uint4(f2bf(a[0], a[1]), f2bf(a[2], a[3]), f2bf(a[4], a[5]), f2bf(a[6], a[7]));
                Ao[1] = make_uint4(f2bf(a[8], a[9]), f2bf(a[10], a[11]), f2bf(a[12], a[13]), f2bf(a[14], a[15]));
                uint4* Bo = reinterpret_cast<uint4*>(Bout + (size_t)gid * 8);
                Bo[0] = make_uint4(f2bf(bb[0], bb[1]), f2bf(bb[2], bb[3]), f2bf(bb[4], bb[5]), f2bf(bb[6], bb[7]));
                Bo[1] = make_uint4(f2bf(bb[8], bb[9]), f2bf(bb[10], bb[11]), f2bf(bb[12], bb[13]), f2bf(bb[14], bb[15]));
            }
        }
    }
}

// ==================== flows (original order, exact fp32) ====================
__global__ __launch_bounds__(256) void flows_noatomic(const int* __restrict__ ei,
                                                      const float* __restrict__ ea,
                                                      const float* __restrict__ Pbuf,
                                                      float* __restrict__ flows_out) {
    int e = blockIdx.x * 256 + threadIdx.x;
    if (e >= N_EDGES) return;
    int s = ei[e];
    int d = ei[N_EDGES + e];
    float ps = Pbuf[s], pd = Pbuf[d];
    float dp2 = ps * ps - pd * pd;
    float k = ea[(size_t)e * F_EDGE];
    float sg = (dp2 > 0.0f) ? 1.0f : ((dp2 < 0.0f) ? -1.0f : 0.0f);
    flows_out[e] = sg * sqrtf(fabsf(dp2) / k + EPSF);
}

// ==================== balance in-flow: segscan over sorted records ====================
__global__ __launch_bounds__(256) void balance_in(const uint4* __restrict__ rec,
                                                  const float* __restrict__ flows,
                                                  const float* __restrict__ x,
                                                  const int* __restrict__ based,
                                                  const int* __restrict__ totd,
                                                  float* __restrict__ bal) {
    __shared__ float acc[NPB];
    int t = threadIdx.x;
    if (t < NPB) acc[t] = 0.0f;
    __syncthreads();
    int b = blockIdx.x;
    int beg = based[b], end = beg + totd[b];
    int lane = t & 63;
    for (int base = beg; base < end; base += 256) {
        int p = base + t;
        bool valid = p < end;
        int key = -1;
        float f = 0.0f;
        if (valid) {
            uint4 r = rec[p];
            key = (int)((r.x >> 17) & 63u);
            f = flows[r.w];
        }
#pragma unroll
        for (int st = 1; st < 64; st <<= 1) {
            int kup = __shfl_up(key, st, 64);
            float v = __shfl_up(f, st, 64);
            if ((lane >= st) && (kup == key)) f += v;
        }
        int knx = __shfl_down(key, 1, 64);
        bool tail = (lane == 63) || (knx != key);
        if (valid && tail) atomicAdd(&acc[key], f);
    }
    __syncthreads();
    if (t < NPB) {
        int gid = (b << 6) + t;
        if (gid < N_NODES) bal[gid] = acc[t] + x[gid * F_NODE + 0];
    }
}

// ==================== balance out-flow + imbalance partial ====================
__global__ __launch_bounds__(256) void balance_out(const unsigned* __restrict__ sbuf,
                                                   const float* __restrict__ flows,
                                                   const int* __restrict__ bases,
                                                   const int* __restrict__ tots,
                                                   const float* __restrict__ bal,
                                                   float* __restrict__ imb2) {
    __shared__ float acc[NPB];
    int t = threadIdx.x;
    if (t < NPB) acc[t] = 0.0f;
    __syncthreads();
    int b = blockIdx.x;
    int beg = bases[b], end = beg + tots[b];
    for (int q = beg + t; q < end; q += 256) {
        unsigned u = sbuf[q];
        atomicAdd(&acc[(u >> 22) & 63u], flows[u & 0x3FFFFFu]);
    }
    __syncthreads();
    if (t < NPB) {
        float v = 0.0f;
        int gid = (b << 6) + t;
        if (gid < N_NODES) {
            float bv = bal[gid] - acc[t];
            v = bv * bv;
        }
#pragma unroll
        for (int off = 32; off > 0; off >>= 1) v += __shfl_down(v, off, 64);
        if (t == 0) atomicAdd(imb2, v);
    }
}

__global__ void fin_kernel(const float* __restrict__ imb2, float* __restrict__ out) {
    out[0] = sqrtf(imb2[0]);
}

// ==================== launch ====================
extern "C" void kernel_launch(void* const* d_in, const int* in_sizes, int n_in,
                              void* d_out, int out_size, void* d_ws, size_t ws_size,
                              hipStream_t stream) {
    const float* x   = (const float*)d_in[0];
    const float* ea  = (const float*)d_in[1];
    const int*   ei  = (const int*)d_in[2];
    const float* W1  = (const float*)d_in[3];
    const float* b1  = (const float*)d_in[4];
    const float* W2  = (const float*)d_in[5];
    const float* b2  = (const float*)d_in[6];
    const float* Wf  = (const float*)d_in[7];
    const float* bf_ = (const float*)d_in[8];
    float* out = (float*)d_out;

    const size_t N = N_NODES, E = N_EDGES;

    // ---- workspace layout (4B elements), ~104 MB ----
    size_t o = 0;
    auto alloc = [&](size_t n) { size_t r = o; o += (n + 3) & ~(size_t)3; return r; };
    size_t o_rec    = alloc(4 * E);
    size_t o_sbuf   = alloc(E);
    size_t o_ghd    = alloc((size_t)G1 * NBK);
    size_t o_ghs    = alloc((size_t)G1 * NBK);
    size_t o_totd   = alloc(NBK);
    size_t o_tots   = alloc(NBK);
    size_t o_based  = alloc(NBK);
    size_t o_bases  = alloc(NBK);
    size_t o_degInv = alloc(N);
    size_t o_A0     = alloc(8 * N);
    size_t o_B0     = alloc(8 * N);
    size_t o_A1     = alloc(8 * N);
    size_t o_B1     = alloc(8 * N);
    size_t o_Pbuf   = alloc(N);
    size_t o_bal    = alloc(N);
    size_t o_imb2   = alloc(16);
    (void)o;

    int* wsi = (int*)d_ws;
    uint4*    rec    = (uint4*)(wsi + o_rec);
    unsigned* sbuf   = (unsigned*)(wsi + o_sbuf);
    int*      ghd    = wsi + o_ghd;
    int*      ghs    = wsi + o_ghs;
    int*      totd   = wsi + o_totd;
    int*      tots   = wsi + o_tots;
    int*      based  = wsi + o_based;
    int*      bases  = wsi + o_bases;
    float*    degInv = (float*)(wsi + o_degInv);
    unsigned* A0     = (unsigned*)(wsi + o_A0);
    unsigned* B0     = (unsigned*)(wsi + o_B0);
    unsigned* A1     = (unsigned*)(wsi + o_A1);
    unsigned* B1     = (unsigned*)(wsi + o_B1);
    float*    Pbuf   = (float*)(wsi + o_Pbuf);
    float*    bal    = (float*)(wsi + o_bal);
    float*    imb2   = (float*)(wsi + o_imb2);

    const int NB = (N_NODES + 255) / 256;   // 391
    const int EB = (N_EDGES + 255) / 256;   // 12500

    hipMemsetAsync(imb2, 0, sizeof(float), stream);

    hist_kernel<<<G1, 256, 0, stream>>>(ei, ghd, ghs);
    scanb_kernel<<<NBK, 64, 0, stream>>>(ghd, ghs, totd, tots);
    totscan_kernel<<<1, 256, 0, stream>>>(totd, tots, based, bases);
    scatter_kernel<<<G1, 256, 0, stream>>>(ei, ea, ghd, ghs, based, bases, rec, sbuf);
    sort_kernel<<<NBK, 256, 0, stream>>>(rec, based, totd, degInv);

    ab_init<<<NB, 256, 0, stream>>>(x, W1, b1, A0, B0);

    for (int l = 0; l < NLAYER; l++) {
        const unsigned* Ain = (l & 1) ? A1 : A0;
        const unsigned* Bin = (l & 1) ? B1 : B0;
        unsigned* Aout = (l & 1) ? A0 : A1;
        unsigned* Bout = (l & 1) ? B0 : B1;
        const float* W1l = W1 + (size_t)l * 24 * HID;
        const float* W2l = W2 + (size_t)l * HID * LD;
        const float* b2l = b2 + (size_t)l * LD;
        if (l < NLAYER - 1) {
            edge_layer<0><<<NBK, 256, 0, stream>>>(rec, Ain, Bin, x, degInv, W1l, W2l, b2l,
                                                   W1 + (size_t)(l + 1) * 24 * HID,
                                                   b1 + (size_t)(l + 1) * HID,
                                                   Wf, bf_, based, totd,
                                                   Aout, Bout, out, Pbuf);
        } else {
            edge_layer<1><<<NBK, 256, 0, stream>>>(rec, Ain, Bin, x, degInv, W1l, W2l, b2l,
                                                   W1, b1, Wf, bf_, based, totd,
                                                   Aout, Bout, out, Pbuf);
        }
    }

    flows_noatomic<<<EB, 256, 0, stream>>>(ei, ea, Pbuf, out + N);
    balance_in<<<NBK, 256, 0, stream>>>(rec, out + N, x, based, totd, bal);
    balance_out<<<NBK, 256, 0, stream>>>(sbuf, out + N, bases, tots, bal, imb2);
    fin_kernel<<<1, 1, 0, stream>>>(imb2, out + (size_t)N + E);
}